// Round 10
// baseline (118.085 us; speedup 1.0000x reference)
//
#include <hip/hip_runtime.h>

#pragma clang fp contract(off)

// ChamferLoss: BS=4, N=M=8192, D=3
// Outputs (concatenated, float):
//   [0*32768 .. )  min over gts  for each pred   [BS, M]
//   [1*32768 .. )  min over preds for each gt    [BS, N]
//   [2*32768 .. )  argmin over gts  (as float)   [BS, M]
//   [3*32768 .. )  argmin over preds (as float)  [BS, N]
//
// Bit-exact numpy fp32 emulation (PASS rounds 6-9), NO FMA anywhere
// (pragma contract(off); ROCm __f*_rn do NOT block contraction):
//   rr = ((x*x + y*y) + z*z)           ascending
//   zz = ((x0*y0 + x1*y1) + x2*y2)     ascending, no FMA
//   P  = ((rr_n + rr_m) - (2*zz))      left-to-right; *2 exact
// v_pk_{mul,add}_f32 = same IEEE-rn per half => bit-exact. zz+zz == 2*zz
// exactly; ts + (-w) == ts - w exactly (neg_lo/neg_hi modifier).
//
// Round 10: r9 counters showed 15.9 VALU inst/pair = scalar codegen (f32x2
// was NOT lowered to v_pk_*). Fix: explicit inline-asm VOP3P, and pack 2
// CANDIDATE rows per f32x2 (tile stored row-pair-interleaved -> ds_read_b128
// gives packed operands directly, zero broadcast movs; queries broadcast
// once outside the loop). QT=4, QBLK=128 -> 512 blocks = 2 blocks/CU
// = 8 waves/SIMD (launch_bounds(1024,8), VGPR<=64).

#define BS     4
#define NPTS   8192
#define CHUNK  1024
#define BLOCK  1024
#define SPLITS 32
#define SLOTS  32                 // query slots per block
#define QT     4                  // queries per thread
#define QBLK   (SLOTS * QT)       // 128 queries per block
#define ROWS   (CHUNK / SPLITS)   // 32 candidate rows per chunk per split
#define RPAIR  (ROWS / 2)         // 16 row-pairs per chunk per split

typedef float f32x2 __attribute__((ext_vector_type(2)));
typedef float f32x4 __attribute__((ext_vector_type(4)));

static __device__ __forceinline__ f32x2 pk_mul(f32x2 a, f32x2 b) {
    f32x2 d;
    asm("v_pk_mul_f32 %0, %1, %2" : "=v"(d) : "v"(a), "v"(b));
    return d;
}
static __device__ __forceinline__ f32x2 pk_add(f32x2 a, f32x2 b) {
    f32x2 d;
    asm("v_pk_add_f32 %0, %1, %2" : "=v"(d) : "v"(a), "v"(b));
    return d;
}
static __device__ __forceinline__ f32x2 pk_sub(f32x2 a, f32x2 b) {
    f32x2 d;   // d = a + (-b), exact IEEE subtract
    asm("v_pk_add_f32 %0, %1, %2 neg_lo:[0,1] neg_hi:[0,1]" : "=v"(d) : "v"(a), "v"(b));
    return d;
}

__global__ __launch_bounds__(BLOCK, 8)
void chamfer_kernel(const float* __restrict__ preds,
                    const float* __restrict__ gts,
                    float* __restrict__ out)
{
#pragma clang fp contract(off)
    const int dir   = blockIdx.z;  // 0: per-pred min over gts, 1: per-gt min over preds
    const int b     = blockIdx.y;
    const int t     = threadIdx.x;
    const int slot  = t & (SLOTS - 1);   // query slot within block
    const int split = t >> 5;            // candidate split
    const int qb    = blockIdx.x * QBLK;

    const float* qbase = (dir == 0 ? preds : gts) + (size_t)b * NPTS * 3;
    const float* rbase = (dir == 0 ? gts : preds) + (size_t)b * NPTS * 3;
    float* outv = out + (size_t)dir       * BS * NPTS + (size_t)b * NPTS;
    float* outi = out + (size_t)(2 + dir) * BS * NPTS + (size_t)b * NPTS;

    // 24KB shared. Main loop: tile (16KB) = shxy4[512] + shzr4[512],
    //   shxy4[i]=(x_{2i},x_{2i+1},y_{2i},y_{2i+1}), shzr4[i]=(z,z,rr,rr pairs).
    // After final barrier: merge scratch shv[32][128] f32 + shi16[32][128] u16.
    __shared__ alignas(16) float smem[6144];
    f32x4* shxy4          = (f32x4*)smem;                 // [512]
    f32x4* shzr4          = (f32x4*)(smem + 2048);        // [512]
    float* shv            = smem;                         // [SPLITS*QBLK]
    unsigned short* shi16 = (unsigned short*)(smem + 4096);

    // QT=4 query points; broadcast into packed pairs ONCE (32 VGPR)
    f32x2 qxx[QT], qyy[QT], qzz[QT], qrr[QT];
#pragma unroll
    for (int j = 0; j < QT; ++j) {
        const int q = qb + j * SLOTS + slot;
        const float x = qbase[(size_t)q * 3 + 0];
        const float y = qbase[(size_t)q * 3 + 1];
        const float z = qbase[(size_t)q * 3 + 2];
        const float a0 = x * x;
        const float a1 = y * y;
        const float a2 = z * z;
        const float rq = (a0 + a1) + a2;   // ascending, no FMA
        qxx[j] = (f32x2){x, x};
        qyy[j] = (f32x2){y, y};
        qzz[j] = (f32x2){z, z};
        qrr[j] = (f32x2){rq, rq};
    }

    float bestv[QT];
    int   besti[QT];
#pragma unroll
    for (int j = 0; j < QT; ++j) { bestv[j] = 3.0e38f; besti[j] = 0; }

    float* xy = smem;          // scalar views for staging
    float* zr = smem + 2048;

    const int nchunks = NPTS / CHUNK;
    for (int c = 0; c < nchunks; ++c) {
        __syncthreads();
        {   // stage: each of 1024 threads loads one point into pair-interleaved tile
            const size_t n = (size_t)c * CHUNK + t;
            const float x = rbase[n * 3 + 0];
            const float y = rbase[n * 3 + 1];
            const float z = rbase[n * 3 + 2];
            const float a0 = x * x;
            const float a1 = y * y;
            const float a2 = z * z;
            const float rr = (a0 + a1) + a2;   // ascending, no FMA
            const int p  = t >> 1;
            const int h  = t & 1;
            xy[p * 4 + h]     = x;
            xy[p * 4 + 2 + h] = y;
            zr[p * 4 + h]     = z;
            zr[p * 4 + 2 + h] = rr;
        }
        __syncthreads();

        const int rp0  = split * RPAIR;
        const int idxb = c * CHUNK + split * ROWS;
        for (int k = 0; k < RPAIR; ++k) {
            const f32x4 axy = shxy4[rp0 + k];
            const f32x4 azr = shzr4[rp0 + k];
            const f32x2 xp = (f32x2){axy[0], axy[1]};
            const f32x2 yp = (f32x2){axy[2], axy[3]};
            const f32x2 zp = (f32x2){azr[0], azr[1]};
            const f32x2 rp2 = (f32x2){azr[2], azr[3]};
            const int idx0 = idxb + 2 * k;
#pragma unroll
            for (int j = 0; j < QT; ++j) {
                // zz ascending ((d0 + d1) + d2), packed IEEE-rn, no FMA
                const f32x2 p0 = pk_mul(xp, qxx[j]);
                const f32x2 p1 = pk_mul(yp, qyy[j]);
                const f32x2 s01 = pk_add(p0, p1);
                const f32x2 p2 = pk_mul(zp, qzz[j]);
                const f32x2 zz = pk_add(s01, p2);
                // ts = rr + rq; w = 2*zz (== zz+zz exact); v = ts - w
                const f32x2 ts = pk_add(rp2, qrr[j]);
                const f32x2 w  = pk_add(zz, zz);
                const f32x2 v  = pk_sub(ts, w);
                // ascending candidate order, strict < => first occurrence
                if (v[0] < bestv[j]) { bestv[j] = v[0]; besti[j] = idx0; }
                if (v[1] < bestv[j]) { bestv[j] = v[1]; besti[j] = idx0 + 1; }
            }
        }
    }

    // ---- Merge over splits; lex (v, idx) min == numpy first-occurrence argmin
    // (valid: v is bit-identical regardless of which split computes it)
    __syncthreads();   // all tile reads done; safe to overwrite smem
#pragma unroll
    for (int j = 0; j < QT; ++j) {
        shv  [split * QBLK + j * SLOTS + slot] = bestv[j];
        shi16[split * QBLK + j * SLOTS + slot] = (unsigned short)besti[j];
    }
    __syncthreads();

    // 8 threads per query: each lex-merges 4 splits, then shfl_xor reduce
    const int qloc = t >> 3;       // 0..127
    const int sl   = t & 7;
    float bv = 3.0e38f;
    int   bi = 0;
#pragma unroll
    for (int k = 0; k < SPLITS / 8; ++k) {
        const int s = sl + k * 8;
        const float v2 = shv[s * QBLK + qloc];
        const int   i2 = shi16[s * QBLK + qloc];
        if (v2 < bv || (v2 == bv && i2 < bi)) { bv = v2; bi = i2; }
    }
#pragma unroll
    for (int o = 1; o < 8; o <<= 1) {
        const float ov = __shfl_xor(bv, o);
        const int   oi = __shfl_xor(bi, o);
        if (ov < bv || (ov == bv && oi < bi)) { bv = ov; bi = oi; }
    }
    if (sl == 0) {
        outv[qb + qloc] = bv;
        outi[qb + qloc] = (float)bi;
    }
}

extern "C" void kernel_launch(void* const* d_in, const int* in_sizes, int n_in,
                              void* d_out, int out_size, void* d_ws, size_t ws_size,
                              hipStream_t stream)
{
    const float* preds = (const float*)d_in[0];  // [BS, M, 3]
    const float* gts   = (const float*)d_in[1];  // [BS, N, 3]
    // d_in[2] = mask, unused (matches reference)
    float* out = (float*)d_out;

    dim3 grid(NPTS / QBLK, BS, 2);   // 64 x 4 x 2 = 512 blocks of 1024
    dim3 block(BLOCK);
    chamfer_kernel<<<grid, block, 0, stream>>>(preds, gts, out);
}